// Round 2
// baseline (718.528 us; speedup 1.0000x reference)
//
#include <hip/hip_runtime.h>
#include <hip/hip_bf16.h>

// Problem constants: B=1, N=16, T=2048, E=64, H=4, D=16
#define N_ 16
#define T_ 2048
#define E_ 64
#define H_ 4
#define D_ 16
#define NH_ 64          // N_*H_
#define SCALE_ 0.125f   // 1/sqrt(E)

// K1: per-head projection  x[N,T,H,D] @ W[D,D] + b -> out[N,H,T,D] (fp32)
__global__ __launch_bounds__(256) void proj_kernel(
    const float* __restrict__ x,
    const float* __restrict__ W,
    const float* __restrict__ b,
    float* __restrict__ out)
{
    __shared__ float Wl[D_ * D_];
    __shared__ float bl[D_];
    int tid = threadIdx.x;
    Wl[tid] = W[tid];                 // D*D == 256 == blockDim
    if (tid < D_) bl[tid] = b[tid];
    __syncthreads();

    int r = blockIdx.x * 256 + tid;      // over N*T*H = 131072
    int h = r & (H_ - 1);
    int t = (r >> 2) & (T_ - 1);
    int n = r >> 13;                     // r / (T_*H_)

    const float4* xp4 = reinterpret_cast<const float4*>(
        x + ((size_t)(n * T_ + t) * E_ + h * D_));
    float xv[D_];
#pragma unroll
    for (int i = 0; i < 4; i++) {
        float4 v = xp4[i];
        xv[4 * i] = v.x; xv[4 * i + 1] = v.y; xv[4 * i + 2] = v.z; xv[4 * i + 3] = v.w;
    }

    float acc[D_];
#pragma unroll
    for (int i = 0; i < D_; i++) acc[i] = bl[i];
#pragma unroll
    for (int j = 0; j < D_; j++) {
        float xj = xv[j];
#pragma unroll
        for (int i = 0; i < D_; i++) acc[i] = fmaf(xj, Wl[j * D_ + i], acc[i]);
    }
    float4* op = reinterpret_cast<float4*>(out + (size_t)((n * H_ + h) * T_ + t) * D_);
#pragma unroll
    for (int i = 0; i < 4; i++)
        op[i] = make_float4(acc[4 * i], acc[4 * i + 1], acc[4 * i + 2], acc[4 * i + 3]);
}

// K2: rl[nh,k] = 1 / sum_q exp(S[q,k]/8)   (softmax over QUERY axis!)
__global__ __launch_bounds__(256) void stats_kernel(
    const float* __restrict__ Qp, const float* __restrict__ Kp,
    float* __restrict__ rl)
{
    __shared__ float Qs[128 * D_];   // 8 KB
    int tid = threadIdx.x;
    int nh = blockIdx.x;
    int k = blockIdx.y * 256 + tid;

    const float4* kp4 = reinterpret_cast<const float4*>(Kp + (size_t)(nh * T_ + k) * D_);
    float4 kr0 = kp4[0], kr1 = kp4[1], kr2 = kp4[2], kr3 = kp4[3];

    const float* qb = Qp + (size_t)nh * T_ * D_;
    float l = 0.f;
    for (int q0 = 0; q0 < T_; q0 += 128) {
        __syncthreads();
        const float4* src = reinterpret_cast<const float4*>(qb + (size_t)q0 * D_);
        float4* dst = reinterpret_cast<float4*>(Qs);
        dst[tid]       = src[tid];
        dst[tid + 256] = src[tid + 256];
        __syncthreads();
        for (int qq = 0; qq < 128; qq++) {
            const float4* qr = reinterpret_cast<const float4*>(Qs + qq * D_);
            float4 a = qr[0], b = qr[1], c = qr[2], d = qr[3];
            float s = a.x * kr0.x;
            s = fmaf(a.y, kr0.y, s); s = fmaf(a.z, kr0.z, s); s = fmaf(a.w, kr0.w, s);
            s = fmaf(b.x, kr1.x, s); s = fmaf(b.y, kr1.y, s);
            s = fmaf(b.z, kr1.z, s); s = fmaf(b.w, kr1.w, s);
            s = fmaf(c.x, kr2.x, s); s = fmaf(c.y, kr2.y, s);
            s = fmaf(c.z, kr2.z, s); s = fmaf(c.w, kr2.w, s);
            s = fmaf(d.x, kr3.x, s); s = fmaf(d.y, kr3.y, s);
            s = fmaf(d.z, kr3.z, s); s = fmaf(d.w, kr3.w, s);
            l += __expf(s * SCALE_);
        }
    }
    rl[nh * T_ + k] = 1.0f / l;
}

// K3: O[n,q,h*16+d] = sum_k exp(S[q,k]/8) * (V[k,d] * rl[k])
__global__ __launch_bounds__(256) void attn_kernel(
    const float* __restrict__ Qp, const float* __restrict__ Kp,
    const float* __restrict__ Vp, const float* __restrict__ rl,
    float* __restrict__ O)
{
    __shared__ float Ks[64 * D_];   // 4 KB
    __shared__ float Vs[64 * D_];   // 4 KB
    int tid = threadIdx.x;
    int nh = blockIdx.x;
    int q = blockIdx.y * 256 + tid;

    const float4* qp4 = reinterpret_cast<const float4*>(Qp + (size_t)(nh * T_ + q) * D_);
    float4 qr0 = qp4[0], qr1 = qp4[1], qr2 = qp4[2], qr3 = qp4[3];

    float acc[D_];
#pragma unroll
    for (int i = 0; i < D_; i++) acc[i] = 0.f;

    const float* kb = Kp + (size_t)nh * T_ * D_;
    const float* vb = Vp + (size_t)nh * T_ * D_;
    const float* rlb = rl + nh * T_;

    int row = tid >> 2;   // staging: float4 #tid -> row tid/4
    for (int k0 = 0; k0 < T_; k0 += 64) {
        __syncthreads();
        reinterpret_cast<float4*>(Ks)[tid] =
            reinterpret_cast<const float4*>(kb + (size_t)k0 * D_)[tid];
        float4 vv = reinterpret_cast<const float4*>(vb + (size_t)k0 * D_)[tid];
        float sc = rlb[k0 + row];
        vv.x *= sc; vv.y *= sc; vv.z *= sc; vv.w *= sc;
        reinterpret_cast<float4*>(Vs)[tid] = vv;
        __syncthreads();
#pragma unroll 4
        for (int kk = 0; kk < 64; kk++) {
            const float4* krow = reinterpret_cast<const float4*>(Ks + kk * D_);
            float4 a = krow[0], b = krow[1], c = krow[2], d = krow[3];
            float s = a.x * qr0.x;
            s = fmaf(a.y, qr0.y, s); s = fmaf(a.z, qr0.z, s); s = fmaf(a.w, qr0.w, s);
            s = fmaf(b.x, qr1.x, s); s = fmaf(b.y, qr1.y, s);
            s = fmaf(b.z, qr1.z, s); s = fmaf(b.w, qr1.w, s);
            s = fmaf(c.x, qr2.x, s); s = fmaf(c.y, qr2.y, s);
            s = fmaf(c.z, qr2.z, s); s = fmaf(c.w, qr2.w, s);
            s = fmaf(d.x, qr3.x, s); s = fmaf(d.y, qr3.y, s);
            s = fmaf(d.z, qr3.z, s); s = fmaf(d.w, qr3.w, s);
            float w = __expf(s * SCALE_);
            const float4* vrow = reinterpret_cast<const float4*>(Vs + kk * D_);
            float4 va = vrow[0], vbv = vrow[1], vc = vrow[2], vd = vrow[3];
            acc[0]  = fmaf(w, va.x,  acc[0]);  acc[1]  = fmaf(w, va.y,  acc[1]);
            acc[2]  = fmaf(w, va.z,  acc[2]);  acc[3]  = fmaf(w, va.w,  acc[3]);
            acc[4]  = fmaf(w, vbv.x, acc[4]);  acc[5]  = fmaf(w, vbv.y, acc[5]);
            acc[6]  = fmaf(w, vbv.z, acc[6]);  acc[7]  = fmaf(w, vbv.w, acc[7]);
            acc[8]  = fmaf(w, vc.x,  acc[8]);  acc[9]  = fmaf(w, vc.y,  acc[9]);
            acc[10] = fmaf(w, vc.z,  acc[10]); acc[11] = fmaf(w, vc.w,  acc[11]);
            acc[12] = fmaf(w, vd.x,  acc[12]); acc[13] = fmaf(w, vd.y,  acc[13]);
            acc[14] = fmaf(w, vd.z,  acc[14]); acc[15] = fmaf(w, vd.w,  acc[15]);
        }
    }
    int n = nh >> 2, h = nh & 3;
    float4* op = reinterpret_cast<float4*>(O + (size_t)(n * T_ + q) * E_ + h * D_);
#pragma unroll
    for (int i = 0; i < 4; i++)
        op[i] = make_float4(acc[4 * i], acc[4 * i + 1], acc[4 * i + 2], acc[4 * i + 3]);
}

// K4: out[r,e] = O[r,:] @ Wfc[:,e] + bfc[e]   (r over N*T, fp32 output)
__global__ __launch_bounds__(256) void fc_kernel(
    const float* __restrict__ O,
    const float* __restrict__ Wfc,
    const float* __restrict__ bfc,
    float* __restrict__ out)
{
    __shared__ float WL[E_ * E_];   // 16 KB
    int tid = threadIdx.x;
    for (int i = tid; i < E_ * E_; i += 256) WL[i] = Wfc[i];
    __syncthreads();

    int gid = blockIdx.x * 256 + tid;
    int r = gid >> 2;          // row in [0, N*T)
    int quarter = gid & 3;     // 16-wide output slice

    const float4* orow = reinterpret_cast<const float4*>(O + (size_t)r * E_);
    float xr[E_];
#pragma unroll
    for (int i = 0; i < 16; i++) {
        float4 v = orow[i];
        xr[4 * i] = v.x; xr[4 * i + 1] = v.y; xr[4 * i + 2] = v.z; xr[4 * i + 3] = v.w;
    }
    float acc[16];
#pragma unroll
    for (int i = 0; i < 16; i++) acc[i] = bfc[quarter * 16 + i];
    for (int e = 0; e < E_; e++) {
        float xv = xr[e];
        const float* w = WL + e * E_ + quarter * 16;
#pragma unroll
        for (int i = 0; i < 16; i++) acc[i] = fmaf(xv, w[i], acc[i]);
    }
    float4* op = reinterpret_cast<float4*>(out + (size_t)r * E_ + quarter * 16);
#pragma unroll
    for (int i = 0; i < 4; i++)
        op[i] = make_float4(acc[4 * i], acc[4 * i + 1], acc[4 * i + 2], acc[4 * i + 3]);
}

extern "C" void kernel_launch(void* const* d_in, const int* in_sizes, int n_in,
                              void* d_out, int out_size, void* d_ws, size_t ws_size,
                              hipStream_t stream) {
    (void)in_sizes; (void)n_in; (void)out_size; (void)ws_size;
    const float* value = (const float*)d_in[0];
    const float* key   = (const float*)d_in[1];
    const float* query = (const float*)d_in[2];
    const float* Wq    = (const float*)d_in[3];
    const float* bq    = (const float*)d_in[4];
    const float* Wk    = (const float*)d_in[5];
    const float* bk    = (const float*)d_in[6];
    const float* Wv    = (const float*)d_in[7];
    const float* bv    = (const float*)d_in[8];
    const float* Wfc   = (const float*)d_in[9];
    const float* bfc   = (const float*)d_in[10];
    float* out = (float*)d_out;

    // Workspace layout (fp32): Qp|Kp|Vp [NH,T,D] (2M floats each), rl [NH*T], O [N,T,E]
    float* ws = (float*)d_ws;
    float* Qp = ws;
    float* Kp = ws + 2097152;
    float* Vp = ws + 4194304;
    float* rl = ws + 6291456;
    float* O  = ws + 6422528;   // total 8519680 floats = 32.5 MB

    proj_kernel<<<512, 256, 0, stream>>>(query, Wq, bq, Qp);
    proj_kernel<<<512, 256, 0, stream>>>(key,   Wk, bk, Kp);
    proj_kernel<<<512, 256, 0, stream>>>(value, Wv, bv, Vp);
    stats_kernel<<<dim3(NH_, T_ / 256), 256, 0, stream>>>(Qp, Kp, rl);
    attn_kernel<<<dim3(NH_, T_ / 256), 256, 0, stream>>>(Qp, Kp, Vp, rl, O);
    fc_kernel<<<512, 256, 0, stream>>>(O, Wfc, bfc, out);
}

// Round 4
// 248.991 us; speedup vs baseline: 2.8858x; 2.8858x over previous
//
#include <hip/hip_runtime.h>

// Problem constants: B=1, N=16, T=2048, E=64, H=4, D=16
#define N_ 16
#define T_ 2048
#define E_ 64
#define H_ 4
#define D_ 16
#define NH_ 64            // N_*H_
#define SEXP_ 0.18033688f // 0.125 * log2(e):  exp(s/8) == exp2(s*SEXP_)

typedef __attribute__((ext_vector_type(4))) _Float16 h4;
typedef __attribute__((ext_vector_type(4))) float f4;

// ---------------------------------------------------------------------------
// K1: Q/K projection -> fp16 row-major [NH][T][D]
//     x[N,T,H,D] @ W[D,D] + b ;  blockIdx.y selects (q|k)
// ---------------------------------------------------------------------------
__global__ __launch_bounds__(256) void proj_qk_kernel(
    const float* __restrict__ xq, const float* __restrict__ Wq, const float* __restrict__ bq,
    const float* __restrict__ xk, const float* __restrict__ Wk, const float* __restrict__ bk,
    _Float16* __restrict__ Qh, _Float16* __restrict__ Kh)
{
    const float* x = blockIdx.y ? xk : xq;
    const float* W = blockIdx.y ? Wk : Wq;
    const float* b = blockIdx.y ? bk : bq;
    _Float16* out  = blockIdx.y ? Kh : Qh;

    __shared__ float Wl[D_ * D_];
    __shared__ float bl[D_];
    int tid = threadIdx.x;
    Wl[tid] = W[tid];
    if (tid < D_) bl[tid] = b[tid];
    __syncthreads();

    int r = blockIdx.x * 256 + tid;      // over N*T*H, h fastest (coalesced reads)
    int h = r & (H_ - 1);
    int t = (r >> 2) & (T_ - 1);
    int n = r >> 13;

    const float4* xp4 = reinterpret_cast<const float4*>(
        x + ((size_t)(n * T_ + t) * E_ + h * D_));
    float xv[D_];
#pragma unroll
    for (int i = 0; i < 4; i++) {
        float4 v = xp4[i];
        xv[4*i] = v.x; xv[4*i+1] = v.y; xv[4*i+2] = v.z; xv[4*i+3] = v.w;
    }
    float acc[D_];
#pragma unroll
    for (int i = 0; i < D_; i++) acc[i] = bl[i];
#pragma unroll
    for (int j = 0; j < D_; j++) {
        float xj = xv[j];
#pragma unroll
        for (int i = 0; i < D_; i++) acc[i] = fmaf(xj, Wl[j * D_ + i], acc[i]);
    }
    _Float16 ob[16];
#pragma unroll
    for (int i = 0; i < D_; i++) ob[i] = (_Float16)acc[i];
    uint4* dst = reinterpret_cast<uint4*>(out + (size_t)((n * H_ + h) * T_ + t) * D_);
    dst[0] = reinterpret_cast<uint4*>(ob)[0];
    dst[1] = reinterpret_cast<uint4*>(ob)[1];
}

// ---------------------------------------------------------------------------
// K2: V projection -> fp16 TRANSPOSED [NH][D][T]
// ---------------------------------------------------------------------------
__global__ __launch_bounds__(256) void proj_tv_kernel(
    const float* __restrict__ x, const float* __restrict__ W, const float* __restrict__ b,
    _Float16* __restrict__ Vt)
{
    __shared__ float Wl[D_ * D_];
    __shared__ float bl[D_];
    int tid = threadIdx.x;
    Wl[tid] = W[tid];
    if (tid < D_) bl[tid] = b[tid];
    __syncthreads();

    int r = blockIdx.x * 256 + tid;      // t fastest (coalesced transposed stores)
    int t = r & (T_ - 1);
    int h = (r >> 11) & (H_ - 1);
    int n = r >> 13;

    const float4* xp4 = reinterpret_cast<const float4*>(
        x + ((size_t)(n * T_ + t) * E_ + h * D_));
    float xv[D_];
#pragma unroll
    for (int i = 0; i < 4; i++) {
        float4 v = xp4[i];
        xv[4*i] = v.x; xv[4*i+1] = v.y; xv[4*i+2] = v.z; xv[4*i+3] = v.w;
    }
    float acc[D_];
#pragma unroll
    for (int i = 0; i < D_; i++) acc[i] = bl[i];
#pragma unroll
    for (int j = 0; j < D_; j++) {
        float xj = xv[j];
#pragma unroll
        for (int i = 0; i < D_; i++) acc[i] = fmaf(xj, Wl[j * D_ + i], acc[i]);
    }
    _Float16* vb = Vt + (size_t)(n * H_ + h) * D_ * T_ + t;
#pragma unroll
    for (int d = 0; d < D_; d++) vb[(size_t)d * T_] = (_Float16)acc[d];
}

// ---------------------------------------------------------------------------
// K3: stats — rl[nh,k] = 1 / sum_q exp(S[q,k]/8), via MFMA S^T = K·Q^T
//     wave handles 2 k-tiles; grid (NH, 16) x 256
// ---------------------------------------------------------------------------
__global__ __launch_bounds__(256) void stats_kernel(
    const _Float16* __restrict__ Qh, const _Float16* __restrict__ Kh,
    float* __restrict__ rl)
{
    int tid = threadIdx.x;
    int lane = tid & 63, wave = tid >> 6;
    int row = lane & 15, quad = lane >> 4;
    int nh = blockIdx.x;
    int kt = (blockIdx.y * 4 + wave) * 2;     // k-tile pair index
    const _Float16* Kb = Kh + (size_t)nh * T_ * D_;
    const _Float16* Qb = Qh + (size_t)nh * T_ * D_;

    h4 a0 = *reinterpret_cast<const h4*>(Kb + (kt * 16 + row) * D_ + quad * 4);
    h4 a1 = *reinterpret_cast<const h4*>(Kb + (kt * 16 + 16 + row) * D_ + quad * 4);
    f4 l0 = {0.f, 0.f, 0.f, 0.f}, l1 = {0.f, 0.f, 0.f, 0.f};
    f4 z  = {0.f, 0.f, 0.f, 0.f};

#pragma unroll 2
    for (int q0 = 0; q0 < T_; q0 += 16) {
        h4 b = *reinterpret_cast<const h4*>(Qb + (q0 + row) * D_ + quad * 4);
        f4 s0 = __builtin_amdgcn_mfma_f32_16x16x16f16(a0, b, z, 0, 0, 0);
        f4 s1 = __builtin_amdgcn_mfma_f32_16x16x16f16(a1, b, z, 0, 0, 0);
#pragma unroll
        for (int i = 0; i < 4; i++) {
            l0[i] += exp2f(s0[i] * SEXP_);
            l1[i] += exp2f(s1[i] * SEXP_);
        }
    }
    // sum over q (= over the 16 lanes of each quad group)
#pragma unroll
    for (int off = 1; off < 16; off <<= 1) {
#pragma unroll
        for (int i = 0; i < 4; i++) {
            l0[i] += __shfl_xor(l0[i], off, 64);
            l1[i] += __shfl_xor(l1[i], off, 64);
        }
    }
    if (row == 0) {
        f4 r0, r1;
#pragma unroll
        for (int i = 0; i < 4; i++) { r0[i] = 1.0f / l0[i]; r1[i] = 1.0f / l1[i]; }
        *reinterpret_cast<f4*>(rl + (size_t)nh * T_ + kt * 16 + quad * 4) = r0;
        *reinterpret_cast<f4*>(rl + (size_t)nh * T_ + kt * 16 + 16 + quad * 4) = r1;
    }
}

// ---------------------------------------------------------------------------
// K4: Vsc[nh][d][t] = Vt[nh][d][t] * rl[nh][t]
// ---------------------------------------------------------------------------
__global__ __launch_bounds__(256) void vscale_kernel(
    const _Float16* __restrict__ Vt, const float* __restrict__ rl,
    _Float16* __restrict__ Vsc)
{
    int idx = blockIdx.x * 256 + threadIdx.x;      // over NH*D*T/8 = 262144
    size_t base = (size_t)idx * 8;
    int t0 = (int)(base & (T_ - 1));
    int dnh = (int)(base >> 11);
    int nh = dnh >> 4;

    union { uint4 u; _Float16 hh[8]; } v;
    v.u = *reinterpret_cast<const uint4*>(Vt + base);
    const f4* rp = reinterpret_cast<const f4*>(rl + (size_t)nh * T_ + t0);
    f4 r0 = rp[0], r1 = rp[1];
#pragma unroll
    for (int i = 0; i < 4; i++) v.hh[i]     = (_Float16)((float)v.hh[i]     * r0[i]);
#pragma unroll
    for (int i = 0; i < 4; i++) v.hh[4 + i] = (_Float16)((float)v.hh[4 + i] * r1[i]);
    *reinterpret_cast<uint4*>(Vsc + base) = v.u;
}

// ---------------------------------------------------------------------------
// K5: attn — O[q,:] = sum_k exp(S[q,k]/8) * Vsc[k,:]
//     S^T tile via MFMA; its C-layout == A-layout of P for the PV MFMA.
//     wave handles 2 q-tiles; grid (NH, 16) x 256.  Output Oh fp16 [N,T,E].
// ---------------------------------------------------------------------------
__global__ __launch_bounds__(256) void attn_kernel(
    const _Float16* __restrict__ Qh, const _Float16* __restrict__ Kh,
    const _Float16* __restrict__ Vsc, _Float16* __restrict__ Oh)
{
    int tid = threadIdx.x;
    int lane = tid & 63, wave = tid >> 6;
    int row = lane & 15, quad = lane >> 4;
    int nh = blockIdx.x;
    int qt = (blockIdx.y * 4 + wave) * 2;     // q-tile pair index
    const _Float16* Kb = Kh + (size_t)nh * T_ * D_;
    const _Float16* Qb = Qh + (size_t)nh * T_ * D_;
    const _Float16* Vb = Vsc + (size_t)nh * D_ * T_ + (size_t)row * T_;

    h4 b0 = *reinterpret_cast<const h4*>(Qb + (qt * 16 + row) * D_ + quad * 4);
    h4 b1 = *reinterpret_cast<const h4*>(Qb + (qt * 16 + 16 + row) * D_ + quad * 4);
    f4 o0 = {0.f, 0.f, 0.f, 0.f}, o1 = {0.f, 0.f, 0.f, 0.f};
    f4 z  = {0.f, 0.f, 0.f, 0.f};

#pragma unroll 2
    for (int k0 = 0; k0 < T_; k0 += 16) {
        h4 a = *reinterpret_cast<const h4*>(Kb + (k0 + row) * D_ + quad * 4);
        h4 v = *reinterpret_cast<const h4*>(Vb + k0 + quad * 4);
        f4 s0 = __builtin_amdgcn_mfma_f32_16x16x16f16(a, b0, z, 0, 0, 0);
        f4 s1 = __builtin_amdgcn_mfma_f32_16x16x16f16(a, b1, z, 0, 0, 0);
        h4 p0, p1;
#pragma unroll
        for (int i = 0; i < 4; i++) {
            p0[i] = (_Float16)exp2f(s0[i] * SEXP_);
            p1[i] = (_Float16)exp2f(s1[i] * SEXP_);
        }
        o0 = __builtin_amdgcn_mfma_f32_16x16x16f16(p0, v, o0, 0, 0, 0);
        o1 = __builtin_amdgcn_mfma_f32_16x16x16f16(p1, v, o1, 0, 0, 0);
    }
    int n = nh >> 2, h = nh & 3;
    _Float16* ob = Oh + (size_t)n * T_ * E_ + h * D_ + row;
#pragma unroll
    for (int i = 0; i < 4; i++) {
        int q0 = qt * 16 + quad * 4 + i;
        ob[(size_t)q0 * E_] = (_Float16)o0[i];
        ob[(size_t)(q0 + 16) * E_] = (_Float16)o1[i];
    }
}

// ---------------------------------------------------------------------------
// K6: convert Wfc fp32 -> fp16
// ---------------------------------------------------------------------------
__global__ __launch_bounds__(256) void wconv_kernel(
    const float* __restrict__ Wfc, _Float16* __restrict__ Wh)
{
    int i = blockIdx.x * 256 + threadIdx.x;    // 4096
    Wh[i] = (_Float16)Wfc[i];
}

// ---------------------------------------------------------------------------
// K7: fc — out[r,e] = Oh[r,:] @ Wfc[:,e] + bfc[e], fp16 MFMA, fp32 out
//     wave: one 16-row M-tile, all 4 e-tiles; total M-tiles = N*T/16 = 2048
//     -> 512 blocks x 4 waves  (R3 bug: launched 2048 blocks -> OOB abort)
// ---------------------------------------------------------------------------
__global__ __launch_bounds__(256) void fc_kernel(
    const _Float16* __restrict__ Oh, const _Float16* __restrict__ Wh,
    const float* __restrict__ bfc, float* __restrict__ out)
{
    int tid = threadIdx.x;
    int lane = tid & 63, wave = tid >> 6;
    int row = lane & 15, quad = lane >> 4;
    int g = blockIdx.x * 4 + wave;             // M-tile id, 2048 total
    int r0 = g * 16;

    h4 a[4];
#pragma unroll
    for (int kc = 0; kc < 4; kc++)
        a[kc] = *reinterpret_cast<const h4*>(Oh + (size_t)(r0 + row) * E_ + kc * 16 + quad * 4);

    f4 acc[4];
#pragma unroll
    for (int ne = 0; ne < 4; ne++) acc[ne] = (f4){0.f, 0.f, 0.f, 0.f};

#pragma unroll
    for (int kc = 0; kc < 4; kc++) {
#pragma unroll
        for (int ne = 0; ne < 4; ne++) {
            h4 bb;
#pragma unroll
            for (int j = 0; j < 4; j++)
                bb[j] = Wh[(size_t)(kc * 16 + quad * 4 + j) * E_ + ne * 16 + row];
            acc[ne] = __builtin_amdgcn_mfma_f32_16x16x16f16(a[kc], bb, acc[ne], 0, 0, 0);
        }
    }
#pragma unroll
    for (int ne = 0; ne < 4; ne++) {
        float bias = bfc[ne * 16 + row];
#pragma unroll
        for (int i = 0; i < 4; i++)
            out[(size_t)(r0 + quad * 4 + i) * E_ + ne * 16 + row] = acc[ne][i] + bias;
    }
}

extern "C" void kernel_launch(void* const* d_in, const int* in_sizes, int n_in,
                              void* d_out, int out_size, void* d_ws, size_t ws_size,
                              hipStream_t stream) {
    (void)in_sizes; (void)n_in; (void)out_size; (void)ws_size;
    const float* value = (const float*)d_in[0];
    const float* key   = (const float*)d_in[1];
    const float* query = (const float*)d_in[2];
    const float* Wq    = (const float*)d_in[3];
    const float* bq    = (const float*)d_in[4];
    const float* Wk    = (const float*)d_in[5];
    const float* bk    = (const float*)d_in[6];
    const float* Wv    = (const float*)d_in[7];
    const float* bv    = (const float*)d_in[8];
    const float* Wfc   = (const float*)d_in[9];
    const float* bfc   = (const float*)d_in[10];
    float* out = (float*)d_out;

    // ws layout (byte offsets): Qh 0 | Kh 4M | Vt 8M | Vsc 12M | Wh 16M | rl 17M | Oh 18M..22M
    char* ws = (char*)d_ws;
    _Float16* Qh  = (_Float16*)(ws);
    _Float16* Kh  = (_Float16*)(ws + (4u << 20));
    _Float16* Vt  = (_Float16*)(ws + (8u << 20));
    _Float16* Vsc = (_Float16*)(ws + (12u << 20));
    _Float16* Wh  = (_Float16*)(ws + (16u << 20));
    float*    rl  = (float*)   (ws + (17u << 20));
    _Float16* Oh  = (_Float16*)(ws + (18u << 20));

    proj_qk_kernel<<<dim3(512, 2), 256, 0, stream>>>(query, Wq, bq, key, Wk, bk, Qh, Kh);
    proj_tv_kernel<<<512, 256, 0, stream>>>(value, Wv, bv, Vt);
    wconv_kernel<<<16, 256, 0, stream>>>(Wfc, Wh);
    stats_kernel<<<dim3(NH_, 16), 256, 0, stream>>>(Qh, Kh, rl);
    vscale_kernel<<<1024, 256, 0, stream>>>(Vt, rl, Vsc);
    attn_kernel<<<dim3(NH_, 16), 256, 0, stream>>>(Qh, Kh, Vsc, Oh);
    fc_kernel<<<512, 256, 0, stream>>>(Oh, Wh, bfc, out);
}

// Round 6
// 209.413 us; speedup vs baseline: 3.4311x; 1.1890x over previous
//
#include <hip/hip_runtime.h>

// Problem constants: B=1, N=16, T=2048, E=64, H=4, D=16
#define N_ 16
#define T_ 2048
#define E_ 64
#define H_ 4
#define D_ 16
#define NH_ 64            // N_*H_
#define SEXP_ 0.18033688f // 0.125 * log2(e):  exp(s/8) == exp2(s*SEXP_)

typedef __attribute__((ext_vector_type(4))) _Float16 h4;
typedef __attribute__((ext_vector_type(2))) __fp16 g2;
typedef __attribute__((ext_vector_type(4))) float f4;

#if __has_builtin(__builtin_amdgcn_exp2f)
__device__ inline float fast_exp2(float x) { return __builtin_amdgcn_exp2f(x); }
#else
__device__ inline float fast_exp2(float x) {
    float r; asm("v_exp_f32 %0, %1" : "=v"(r) : "v"(x)); return r;
}
#endif

// pack 4 floats -> h4 via two v_cvt_pkrtz_f16_f32
__device__ inline h4 pack4_f16(float a, float b, float c, float d) {
    union { g2 g[2]; h4 h; } u;
    u.g[0] = __builtin_amdgcn_cvt_pkrtz(a, b);
    u.g[1] = __builtin_amdgcn_cvt_pkrtz(c, d);
    return u.h;
}

// ---------------------------------------------------------------------------
// K1: Q/K projection -> fp16 row-major [NH][T][D]
//     Q side is PRE-SCALED by SEXP_ so MFMA S output is already exp2-ready.
// ---------------------------------------------------------------------------
__global__ __launch_bounds__(256) void proj_qk_kernel(
    const float* __restrict__ xq, const float* __restrict__ Wq, const float* __restrict__ bq,
    const float* __restrict__ xk, const float* __restrict__ Wk, const float* __restrict__ bk,
    _Float16* __restrict__ Qh, _Float16* __restrict__ Kh)
{
    const float* x = blockIdx.y ? xk : xq;
    const float* W = blockIdx.y ? Wk : Wq;
    const float* b = blockIdx.y ? bk : bq;
    _Float16* out  = blockIdx.y ? Kh : Qh;
    const float sc = blockIdx.y ? 1.0f : SEXP_;

    __shared__ float Wl[D_ * D_];
    __shared__ float bl[D_];
    int tid = threadIdx.x;
    Wl[tid] = W[tid];
    if (tid < D_) bl[tid] = b[tid];
    __syncthreads();

    int r = blockIdx.x * 256 + tid;      // over N*T*H, h fastest (coalesced reads)
    int h = r & (H_ - 1);
    int t = (r >> 2) & (T_ - 1);
    int n = r >> 13;

    const float4* xp4 = reinterpret_cast<const float4*>(
        x + ((size_t)(n * T_ + t) * E_ + h * D_));
    float xv[D_];
#pragma unroll
    for (int i = 0; i < 4; i++) {
        float4 v = xp4[i];
        xv[4*i] = v.x; xv[4*i+1] = v.y; xv[4*i+2] = v.z; xv[4*i+3] = v.w;
    }
    float acc[D_];
#pragma unroll
    for (int i = 0; i < D_; i++) acc[i] = bl[i];
#pragma unroll
    for (int j = 0; j < D_; j++) {
        float xj = xv[j];
#pragma unroll
        for (int i = 0; i < D_; i++) acc[i] = fmaf(xj, Wl[j * D_ + i], acc[i]);
    }
    _Float16 ob[16];
#pragma unroll
    for (int i = 0; i < D_; i++) ob[i] = (_Float16)(acc[i] * sc);
    uint4* dst = reinterpret_cast<uint4*>(out + (size_t)((n * H_ + h) * T_ + t) * D_);
    dst[0] = reinterpret_cast<uint4*>(ob)[0];
    dst[1] = reinterpret_cast<uint4*>(ob)[1];
}

// ---------------------------------------------------------------------------
// K2: V projection -> fp16 TRANSPOSED [NH][D][T]
// ---------------------------------------------------------------------------
__global__ __launch_bounds__(256) void proj_tv_kernel(
    const float* __restrict__ x, const float* __restrict__ W, const float* __restrict__ b,
    _Float16* __restrict__ Vt)
{
    __shared__ float Wl[D_ * D_];
    __shared__ float bl[D_];
    int tid = threadIdx.x;
    Wl[tid] = W[tid];
    if (tid < D_) bl[tid] = b[tid];
    __syncthreads();

    int r = blockIdx.x * 256 + tid;      // t fastest (coalesced transposed stores)
    int t = r & (T_ - 1);
    int h = (r >> 11) & (H_ - 1);
    int n = r >> 13;

    const float4* xp4 = reinterpret_cast<const float4*>(
        x + ((size_t)(n * T_ + t) * E_ + h * D_));
    float xv[D_];
#pragma unroll
    for (int i = 0; i < 4; i++) {
        float4 v = xp4[i];
        xv[4*i] = v.x; xv[4*i+1] = v.y; xv[4*i+2] = v.z; xv[4*i+3] = v.w;
    }
    float acc[D_];
#pragma unroll
    for (int i = 0; i < D_; i++) acc[i] = bl[i];
#pragma unroll
    for (int j = 0; j < D_; j++) {
        float xj = xv[j];
#pragma unroll
        for (int i = 0; i < D_; i++) acc[i] = fmaf(xj, Wl[j * D_ + i], acc[i]);
    }
    _Float16* vb = Vt + (size_t)(n * H_ + h) * D_ * T_ + t;
#pragma unroll
    for (int d = 0; d < D_; d++) vb[(size_t)d * T_] = (_Float16)acc[d];
}

// ---------------------------------------------------------------------------
// K3: stats — rl[nh,k] = 1 / sum_q exp2(S'[q,k]), via MFMA S'^T = K·Q'^T
//     (Q' pre-scaled).  wave handles 2 k-tiles; grid (NH, 16) x 256
// ---------------------------------------------------------------------------
__global__ __launch_bounds__(256) void stats_kernel(
    const _Float16* __restrict__ Qh, const _Float16* __restrict__ Kh,
    float* __restrict__ rl)
{
    int tid = threadIdx.x;
    int lane = tid & 63, wave = tid >> 6;
    int row = lane & 15, quad = lane >> 4;
    int nh = blockIdx.x;
    int kt = (blockIdx.y * 4 + wave) * 2;     // k-tile pair index
    const _Float16* Kb = Kh + (size_t)nh * T_ * D_;
    const _Float16* Qb = Qh + (size_t)nh * T_ * D_;

    h4 a0 = *reinterpret_cast<const h4*>(Kb + (kt * 16 + row) * D_ + quad * 4);
    h4 a1 = *reinterpret_cast<const h4*>(Kb + (kt * 16 + 16 + row) * D_ + quad * 4);
    f4 l0 = {0.f, 0.f, 0.f, 0.f}, l1 = {0.f, 0.f, 0.f, 0.f};
    f4 z  = {0.f, 0.f, 0.f, 0.f};

#pragma unroll 4
    for (int q0 = 0; q0 < T_; q0 += 16) {
        h4 b = *reinterpret_cast<const h4*>(Qb + (q0 + row) * D_ + quad * 4);
        f4 s0 = __builtin_amdgcn_mfma_f32_16x16x16f16(a0, b, z, 0, 0, 0);
        f4 s1 = __builtin_amdgcn_mfma_f32_16x16x16f16(a1, b, z, 0, 0, 0);
#pragma unroll
        for (int i = 0; i < 4; i++) {
            l0[i] += fast_exp2(s0[i]);
            l1[i] += fast_exp2(s1[i]);
        }
    }
    // sum over q (= over the 16 lanes of each quad group)
#pragma unroll
    for (int off = 1; off < 16; off <<= 1) {
#pragma unroll
        for (int i = 0; i < 4; i++) {
            l0[i] += __shfl_xor(l0[i], off, 64);
            l1[i] += __shfl_xor(l1[i], off, 64);
        }
    }
    if (row == 0) {
        f4 r0, r1;
#pragma unroll
        for (int i = 0; i < 4; i++) { r0[i] = 1.0f / l0[i]; r1[i] = 1.0f / l1[i]; }
        *reinterpret_cast<f4*>(rl + (size_t)nh * T_ + kt * 16 + quad * 4) = r0;
        *reinterpret_cast<f4*>(rl + (size_t)nh * T_ + kt * 16 + 16 + quad * 4) = r1;
    }
}

// ---------------------------------------------------------------------------
// K4: Vsc[nh][d][t] = Vt[nh][d][t] * rl[nh][t]
// ---------------------------------------------------------------------------
__global__ __launch_bounds__(256) void vscale_kernel(
    const _Float16* __restrict__ Vt, const float* __restrict__ rl,
    _Float16* __restrict__ Vsc)
{
    int idx = blockIdx.x * 256 + threadIdx.x;      // over NH*D*T/8 = 262144
    size_t base = (size_t)idx * 8;
    int t0 = (int)(base & (T_ - 1));
    int dnh = (int)(base >> 11);
    int nh = dnh >> 4;

    union { uint4 u; _Float16 hh[8]; } v;
    v.u = *reinterpret_cast<const uint4*>(Vt + base);
    const f4* rp = reinterpret_cast<const f4*>(rl + (size_t)nh * T_ + t0);
    f4 r0 = rp[0], r1 = rp[1];
#pragma unroll
    for (int i = 0; i < 4; i++) v.hh[i]     = (_Float16)((float)v.hh[i]     * r0[i]);
#pragma unroll
    for (int i = 0; i < 4; i++) v.hh[4 + i] = (_Float16)((float)v.hh[4 + i] * r1[i]);
    *reinterpret_cast<uint4*>(Vsc + base) = v.u;
}

// ---------------------------------------------------------------------------
// K5: attn — O[q,:] = sum_k exp2(S'[q,k]) * Vsc[k,:]
//     S'^T tile via MFMA; its C-layout == A-layout of P for the PV MFMA.
//     wave handles 2 q-tiles; grid (NH, 16) x 256.  Output Oh fp16 [N,T,E].
// ---------------------------------------------------------------------------
__global__ __launch_bounds__(256) void attn_kernel(
    const _Float16* __restrict__ Qh, const _Float16* __restrict__ Kh,
    const _Float16* __restrict__ Vsc, _Float16* __restrict__ Oh)
{
    int tid = threadIdx.x;
    int lane = tid & 63, wave = tid >> 6;
    int row = lane & 15, quad = lane >> 4;
    int nh = blockIdx.x;
    int qt = (blockIdx.y * 4 + wave) * 2;     // q-tile pair index
    const _Float16* Kb = Kh + (size_t)nh * T_ * D_;
    const _Float16* Qb = Qh + (size_t)nh * T_ * D_;
    const _Float16* Vb = Vsc + (size_t)nh * D_ * T_ + (size_t)row * T_;

    h4 b0 = *reinterpret_cast<const h4*>(Qb + (qt * 16 + row) * D_ + quad * 4);
    h4 b1 = *reinterpret_cast<const h4*>(Qb + (qt * 16 + 16 + row) * D_ + quad * 4);
    f4 o0 = {0.f, 0.f, 0.f, 0.f}, o1 = {0.f, 0.f, 0.f, 0.f};
    f4 z  = {0.f, 0.f, 0.f, 0.f};

#pragma unroll 4
    for (int k0 = 0; k0 < T_; k0 += 16) {
        h4 a = *reinterpret_cast<const h4*>(Kb + (k0 + row) * D_ + quad * 4);
        h4 v = *reinterpret_cast<const h4*>(Vb + k0 + quad * 4);
        f4 s0 = __builtin_amdgcn_mfma_f32_16x16x16f16(a, b0, z, 0, 0, 0);
        f4 s1 = __builtin_amdgcn_mfma_f32_16x16x16f16(a, b1, z, 0, 0, 0);
        h4 p0 = pack4_f16(fast_exp2(s0[0]), fast_exp2(s0[1]),
                          fast_exp2(s0[2]), fast_exp2(s0[3]));
        h4 p1 = pack4_f16(fast_exp2(s1[0]), fast_exp2(s1[1]),
                          fast_exp2(s1[2]), fast_exp2(s1[3]));
        o0 = __builtin_amdgcn_mfma_f32_16x16x16f16(p0, v, o0, 0, 0, 0);
        o1 = __builtin_amdgcn_mfma_f32_16x16x16f16(p1, v, o1, 0, 0, 0);
    }
    int n = nh >> 2, h = nh & 3;
    _Float16* ob = Oh + (size_t)n * T_ * E_ + h * D_ + row;
#pragma unroll
    for (int i = 0; i < 4; i++) {
        int q0 = qt * 16 + quad * 4 + i;
        ob[(size_t)q0 * E_] = (_Float16)o0[i];
        ob[(size_t)(q0 + 16) * E_] = (_Float16)o1[i];
    }
}

// ---------------------------------------------------------------------------
// K6: convert Wfc fp32 -> fp16
// ---------------------------------------------------------------------------
__global__ __launch_bounds__(256) void wconv_kernel(
    const float* __restrict__ Wfc, _Float16* __restrict__ Wh)
{
    int i = blockIdx.x * 256 + threadIdx.x;    // 4096
    Wh[i] = (_Float16)Wfc[i];
}

// ---------------------------------------------------------------------------
// K7: fc — out[r,e] = Oh[r,:] @ Wfc[:,e] + bfc[e], fp16 MFMA, fp32 out
//     wave: one 16-row M-tile, all 4 e-tiles; total M-tiles = 2048 -> 512 blocks
// ---------------------------------------------------------------------------
__global__ __launch_bounds__(256) void fc_kernel(
    const _Float16* __restrict__ Oh, const _Float16* __restrict__ Wh,
    const float* __restrict__ bfc, float* __restrict__ out)
{
    int tid = threadIdx.x;
    int lane = tid & 63, wave = tid >> 6;
    int row = lane & 15, quad = lane >> 4;
    int g = blockIdx.x * 4 + wave;             // M-tile id, 2048 total
    int r0 = g * 16;

    h4 a[4];
#pragma unroll
    for (int kc = 0; kc < 4; kc++)
        a[kc] = *reinterpret_cast<const h4*>(Oh + (size_t)(r0 + row) * E_ + kc * 16 + quad * 4);

    f4 acc[4];
#pragma unroll
    for (int ne = 0; ne < 4; ne++) acc[ne] = (f4){0.f, 0.f, 0.f, 0.f};

#pragma unroll
    for (int kc = 0; kc < 4; kc++) {
#pragma unroll
        for (int ne = 0; ne < 4; ne++) {
            h4 bb;
#pragma unroll
            for (int j = 0; j < 4; j++)
                bb[j] = Wh[(size_t)(kc * 16 + quad * 4 + j) * E_ + ne * 16 + row];
            acc[ne] = __builtin_amdgcn_mfma_f32_16x16x16f16(a[kc], bb, acc[ne], 0, 0, 0);
        }
    }
#pragma unroll
    for (int ne = 0; ne < 4; ne++) {
        float bias = bfc[ne * 16 + row];
#pragma unroll
        for (int i = 0; i < 4; i++)
            out[(size_t)(r0 + quad * 4 + i) * E_ + ne * 16 + row] = acc[ne][i] + bias;
    }
}

extern "C" void kernel_launch(void* const* d_in, const int* in_sizes, int n_in,
                              void* d_out, int out_size, void* d_ws, size_t ws_size,
                              hipStream_t stream) {
    (void)in_sizes; (void)n_in; (void)out_size; (void)ws_size;
    const float* value = (const float*)d_in[0];
    const float* key   = (const float*)d_in[1];
    const float* query = (const float*)d_in[2];
    const float* Wq    = (const float*)d_in[3];
    const float* bq    = (const float*)d_in[4];
    const float* Wk    = (const float*)d_in[5];
    const float* bk    = (const float*)d_in[6];
    const float* Wv    = (const float*)d_in[7];
    const float* bv    = (const float*)d_in[8];
    const float* Wfc   = (const float*)d_in[9];
    const float* bfc   = (const float*)d_in[10];
    float* out = (float*)d_out;

    // ws layout (byte offsets): Qh 0 | Kh 4M | Vt 8M | Vsc 12M | Wh 16M | rl 17M | Oh 18M..22M
    char* ws = (char*)d_ws;
    _Float16* Qh  = (_Float16*)(ws);
    _Float16* Kh  = (_Float16*)(ws + (4u << 20));
    _Float16* Vt  = (_Float16*)(ws + (8u << 20));
    _Float16* Vsc = (_Float16*)(ws + (12u << 20));
    _Float16* Wh  = (_Float16*)(ws + (16u << 20));
    float*    rl  = (float*)   (ws + (17u << 20));
    _Float16* Oh  = (_Float16*)(ws + (18u << 20));

    proj_qk_kernel<<<dim3(512, 2), 256, 0, stream>>>(query, Wq, bq, key, Wk, bk, Qh, Kh);
    proj_tv_kernel<<<512, 256, 0, stream>>>(value, Wv, bv, Vt);
    wconv_kernel<<<16, 256, 0, stream>>>(Wfc, Wh);
    stats_kernel<<<dim3(NH_, 16), 256, 0, stream>>>(Qh, Kh, rl);
    vscale_kernel<<<1024, 256, 0, stream>>>(Vt, rl, Vsc);
    attn_kernel<<<dim3(NH_, 16), 256, 0, stream>>>(Qh, Kh, Vsc, Oh);
    fc_kernel<<<512, 256, 0, stream>>>(Oh, Wh, bfc, out);
}

// Round 7
// 201.666 us; speedup vs baseline: 3.5630x; 1.0384x over previous
//
#include <hip/hip_runtime.h>

// Problem constants: B=1, N=16, T=2048, E=64, H=4, D=16
#define N_ 16
#define T_ 2048
#define E_ 64
#define H_ 4
#define D_ 16
#define NH_ 64            // N_*H_
#define SEXP_ 0.18033688f // 0.125 * log2(e):  exp(s/8) == exp2(s*SEXP_)

typedef __attribute__((ext_vector_type(4))) _Float16 h4;
typedef __attribute__((ext_vector_type(8))) _Float16 h8;
typedef __attribute__((ext_vector_type(2))) __fp16 g2;
typedef __attribute__((ext_vector_type(4))) float f4;

#if __has_builtin(__builtin_amdgcn_exp2f)
__device__ inline float fast_exp2(float x) { return __builtin_amdgcn_exp2f(x); }
#else
__device__ inline float fast_exp2(float x) {
    float r; asm("v_exp_f32 %0, %1" : "=v"(r) : "v"(x)); return r;
}
#endif

// pack 4 floats -> h4 via two v_cvt_pkrtz_f16_f32
__device__ inline h4 pack4_f16(float a, float b, float c, float d) {
    union { g2 g[2]; h4 h; } u;
    u.g[0] = __builtin_amdgcn_cvt_pkrtz(a, b);
    u.g[1] = __builtin_amdgcn_cvt_pkrtz(c, d);
    return u.h;
}

// ---------------------------------------------------------------------------
// K1: fused projections.
//   y=0: Q -> fp16 [NH][T][D], pre-scaled by SEXP_
//   y=1: K -> fp16 [NH][T][D]
//   y=2: V -> fp16 TRANSPOSED [NH][D][T]
//   y=3: (first 16 blocks) Wfc fp32 [64][64] -> Wt fp16 transposed [64][64]
// ---------------------------------------------------------------------------
__global__ __launch_bounds__(256) void proj_kernel(
    const float* __restrict__ xq, const float* __restrict__ Wq, const float* __restrict__ bq,
    const float* __restrict__ xk, const float* __restrict__ Wk, const float* __restrict__ bk,
    const float* __restrict__ xv, const float* __restrict__ Wv, const float* __restrict__ bv,
    const float* __restrict__ Wfc,
    _Float16* __restrict__ Qh, _Float16* __restrict__ Kh, _Float16* __restrict__ Vt,
    _Float16* __restrict__ Wt)
{
    int tid = threadIdx.x;
    int y = blockIdx.y;
    if (y == 3) {
        if (blockIdx.x < 16) {
            int k = blockIdx.x * 4 + (tid >> 6);
            int e = tid & 63;
            Wt[e * 64 + k] = (_Float16)Wfc[k * 64 + e];
        }
        return;
    }
    const float* x = (y == 0) ? xq : (y == 1) ? xk : xv;
    const float* W = (y == 0) ? Wq : (y == 1) ? Wk : Wv;
    const float* b = (y == 0) ? bq : (y == 1) ? bk : bv;
    const float sc = (y == 0) ? SEXP_ : 1.0f;

    __shared__ float Wl[D_ * D_];
    __shared__ float bl[D_];
    Wl[tid] = W[tid];
    if (tid < D_) bl[tid] = b[tid];
    __syncthreads();

    int r = blockIdx.x * 256 + tid;
    int h, t, n;
    if (y == 2) {          // t fastest: coalesced transposed stores
        t = r & (T_ - 1);
        h = (r >> 11) & (H_ - 1);
        n = r >> 13;
    } else {               // h fastest: coalesced reads
        h = r & (H_ - 1);
        t = (r >> 2) & (T_ - 1);
        n = r >> 13;
    }

    const float4* xp4 = reinterpret_cast<const float4*>(
        x + ((size_t)(n * T_ + t) * E_ + h * D_));
    float xv_[D_];
#pragma unroll
    for (int i = 0; i < 4; i++) {
        float4 v = xp4[i];
        xv_[4*i] = v.x; xv_[4*i+1] = v.y; xv_[4*i+2] = v.z; xv_[4*i+3] = v.w;
    }
    float acc[D_];
#pragma unroll
    for (int i = 0; i < D_; i++) acc[i] = bl[i];
#pragma unroll
    for (int j = 0; j < D_; j++) {
        float xj = xv_[j];
#pragma unroll
        for (int i = 0; i < D_; i++) acc[i] = fmaf(xj, Wl[j * D_ + i], acc[i]);
    }
    if (y == 2) {
        _Float16* vb = Vt + (size_t)(n * H_ + h) * D_ * T_ + t;
#pragma unroll
        for (int d = 0; d < D_; d++) vb[(size_t)d * T_] = (_Float16)acc[d];
    } else {
        _Float16 ob[16];
#pragma unroll
        for (int i = 0; i < D_; i++) ob[i] = (_Float16)(acc[i] * sc);
        _Float16* out = (y == 0) ? Qh : Kh;
        uint4* dst = reinterpret_cast<uint4*>(out + (size_t)((n * H_ + h) * T_ + t) * D_);
        dst[0] = reinterpret_cast<uint4*>(ob)[0];
        dst[1] = reinterpret_cast<uint4*>(ob)[1];
    }
}

// ---------------------------------------------------------------------------
// K2: stats+vscale — per (nh, k-column): l[k] = sum_q exp2(S'[q,k]), then
//     Vsc[d][k] = Vt[d][k] / l[k].  Wave holds 4 k-tiles; grid (NH, 8) x 256.
// ---------------------------------------------------------------------------
__global__ __launch_bounds__(256) void stats_kernel(
    const _Float16* __restrict__ Qh, const _Float16* __restrict__ Kh,
    const _Float16* __restrict__ Vt, _Float16* __restrict__ Vsc)
{
    int tid = threadIdx.x;
    int lane = tid & 63, wave = tid >> 6;
    int row = lane & 15, quad = lane >> 4;
    int nh = blockIdx.x;
    int kt0 = (blockIdx.y * 4 + wave) * 4;    // first of 4 k-tiles
    const _Float16* Kb = Kh + (size_t)nh * T_ * D_;
    const _Float16* Qb = Qh + (size_t)nh * T_ * D_;

    h4 a[4];
#pragma unroll
    for (int j = 0; j < 4; j++)
        a[j] = *reinterpret_cast<const h4*>(Kb + ((kt0 + j) * 16 + row) * D_ + quad * 4);

    f4 l[4];
#pragma unroll
    for (int j = 0; j < 4; j++) l[j] = (f4){0.f, 0.f, 0.f, 0.f};
    f4 z = {0.f, 0.f, 0.f, 0.f};

#pragma unroll 4
    for (int q0 = 0; q0 < T_; q0 += 16) {
        h4 b = *reinterpret_cast<const h4*>(Qb + (q0 + row) * D_ + quad * 4);
#pragma unroll
        for (int j = 0; j < 4; j++) {
            f4 s = __builtin_amdgcn_mfma_f32_16x16x16f16(a[j], b, z, 0, 0, 0);
#pragma unroll
            for (int i = 0; i < 4; i++) l[j][i] += fast_exp2(s[i]);
        }
    }
    // butterfly sum over the 16 "q-row" lanes of each quad group
#pragma unroll
    for (int off = 1; off < 16; off <<= 1)
#pragma unroll
        for (int j = 0; j < 4; j++)
#pragma unroll
            for (int i = 0; i < 4; i++)
                l[j][i] += __shfl_xor(l[j][i], off, 64);

    // every lane now holds sums for k = (kt0+j)*16 + quad*4 + i
    f4 rr[4];
#pragma unroll
    for (int j = 0; j < 4; j++)
#pragma unroll
        for (int i = 0; i < 4; i++) rr[j][i] = 1.0f / l[j][i];

    // fused vscale: lane (d=row, quad) scales V[d][t0..t0+3] of each tile
    const _Float16* vb = Vt + (size_t)nh * D_ * T_ + (size_t)row * T_;
    _Float16* vs = Vsc + (size_t)nh * D_ * T_ + (size_t)row * T_;
#pragma unroll
    for (int j = 0; j < 4; j++) {
        int t0 = (kt0 + j) * 16 + quad * 4;
        union { uint2 u; _Float16 hh[4]; } v;
        v.u = *reinterpret_cast<const uint2*>(vb + t0);
        h4 sv = pack4_f16((float)v.hh[0] * rr[j][0], (float)v.hh[1] * rr[j][1],
                          (float)v.hh[2] * rr[j][2], (float)v.hh[3] * rr[j][3]);
        union { h4 h; uint2 u; } o; o.h = sv;
        *reinterpret_cast<uint2*>(vs + t0) = o.u;
    }
}

// ---------------------------------------------------------------------------
// K3: attn — O[q,:] = sum_k exp2(S'[q,k]) * Vsc[k,:]
//     Wave holds 4 q-tiles.  Per 32-k: two k16 S-MFMAs with PERMUTED K rows
//     (perm(r)=(r>>2)*8+(r&3), +4) so stacked C-outputs form the 8-elem
//     A-fragment of one 16x16x32 PV MFMA.  grid (NH, 8) x 256.
// ---------------------------------------------------------------------------
__global__ __launch_bounds__(256) void attn_kernel(
    const _Float16* __restrict__ Qh, const _Float16* __restrict__ Kh,
    const _Float16* __restrict__ Vsc, _Float16* __restrict__ Oh)
{
    int tid = threadIdx.x;
    int lane = tid & 63, wave = tid >> 6;
    int row = lane & 15, quad = lane >> 4;
    int nh = blockIdx.x;
    int qt0 = (blockIdx.y * 4 + wave) * 4;    // first of 4 q-tiles
    const _Float16* Kb = Kh + (size_t)nh * T_ * D_;
    const _Float16* Qb = Qh + (size_t)nh * T_ * D_;
    const _Float16* Vb = Vsc + (size_t)nh * D_ * T_ + (size_t)row * T_;

    h4 b[4];
#pragma unroll
    for (int j = 0; j < 4; j++)
        b[j] = *reinterpret_cast<const h4*>(Qb + ((qt0 + j) * 16 + row) * D_ + quad * 4);

    f4 o[4];
#pragma unroll
    for (int j = 0; j < 4; j++) o[j] = (f4){0.f, 0.f, 0.f, 0.f};
    f4 z = {0.f, 0.f, 0.f, 0.f};

    int pr = ((row & 12) << 1) | (row & 3);   // permuted K-row offset

#pragma unroll 2
    for (int k0 = 0; k0 < T_; k0 += 32) {
        h4 a0 = *reinterpret_cast<const h4*>(Kb + (k0 + pr) * D_ + quad * 4);
        h4 a1 = *reinterpret_cast<const h4*>(Kb + (k0 + pr + 4) * D_ + quad * 4);
        h8 v = *reinterpret_cast<const h8*>(Vb + k0 + quad * 8);
#pragma unroll
        for (int j = 0; j < 4; j++) {
            f4 s0 = __builtin_amdgcn_mfma_f32_16x16x16f16(a0, b[j], z, 0, 0, 0);
            f4 s1 = __builtin_amdgcn_mfma_f32_16x16x16f16(a1, b[j], z, 0, 0, 0);
            union { h4 h[2]; h8 h8v; } p;
            p.h[0] = pack4_f16(fast_exp2(s0[0]), fast_exp2(s0[1]),
                               fast_exp2(s0[2]), fast_exp2(s0[3]));
            p.h[1] = pack4_f16(fast_exp2(s1[0]), fast_exp2(s1[1]),
                               fast_exp2(s1[2]), fast_exp2(s1[3]));
            o[j] = __builtin_amdgcn_mfma_f32_16x16x32_f16(p.h8v, v, o[j], 0, 0, 0);
        }
    }
    int n = nh >> 2, h = nh & 3;
    _Float16* ob = Oh + (size_t)n * T_ * E_ + h * D_ + row;
#pragma unroll
    for (int j = 0; j < 4; j++)
#pragma unroll
        for (int i = 0; i < 4; i++) {
            int q0 = (qt0 + j) * 16 + quad * 4 + i;
            ob[(size_t)q0 * E_] = (_Float16)o[j][i];
        }
}

// ---------------------------------------------------------------------------
// K4: fc — out[r,e] = Oh[r,:] @ Wfc[:,e] + bfc[e] via 16x16x32 MFMA on Wt.
//     wave: one 16-row M-tile, 4 e-tiles, K=64 as 2x32; 2048 tiles -> 512 blk
// ---------------------------------------------------------------------------
__global__ __launch_bounds__(256) void fc_kernel(
    const _Float16* __restrict__ Oh, const _Float16* __restrict__ Wt,
    const float* __restrict__ bfc, float* __restrict__ out)
{
    int tid = threadIdx.x;
    int lane = tid & 63, wave = tid >> 6;
    int row = lane & 15, quad = lane >> 4;
    int g = blockIdx.x * 4 + wave;             // M-tile id, 2048 total
    int r0 = g * 16;

    h8 a0 = *reinterpret_cast<const h8*>(Oh + (size_t)(r0 + row) * E_ + quad * 8);
    h8 a1 = *reinterpret_cast<const h8*>(Oh + (size_t)(r0 + row) * E_ + 32 + quad * 8);

    f4 acc[4];
#pragma unroll
    for (int ne = 0; ne < 4; ne++) {
        const _Float16* wtb = Wt + (size_t)(ne * 16 + row) * 64;
        h8 b0 = *reinterpret_cast<const h8*>(wtb + quad * 8);
        h8 b1 = *reinterpret_cast<const h8*>(wtb + 32 + quad * 8);
        acc[ne] = __builtin_amdgcn_mfma_f32_16x16x32_f16(a0, b0, (f4){0.f,0.f,0.f,0.f}, 0, 0, 0);
        acc[ne] = __builtin_amdgcn_mfma_f32_16x16x32_f16(a1, b1, acc[ne], 0, 0, 0);
    }
#pragma unroll
    for (int ne = 0; ne < 4; ne++) {
        float bias = bfc[ne * 16 + row];
#pragma unroll
        for (int i = 0; i < 4; i++)
            out[(size_t)(r0 + quad * 4 + i) * E_ + ne * 16 + row] = acc[ne][i] + bias;
    }
}

extern "C" void kernel_launch(void* const* d_in, const int* in_sizes, int n_in,
                              void* d_out, int out_size, void* d_ws, size_t ws_size,
                              hipStream_t stream) {
    (void)in_sizes; (void)n_in; (void)out_size; (void)ws_size;
    const float* value = (const float*)d_in[0];
    const float* key   = (const float*)d_in[1];
    const float* query = (const float*)d_in[2];
    const float* Wq    = (const float*)d_in[3];
    const float* bq    = (const float*)d_in[4];
    const float* Wk    = (const float*)d_in[5];
    const float* bk    = (const float*)d_in[6];
    const float* Wv    = (const float*)d_in[7];
    const float* bv    = (const float*)d_in[8];
    const float* Wfc   = (const float*)d_in[9];
    const float* bfc   = (const float*)d_in[10];
    float* out = (float*)d_out;

    // ws: Qh 0 | Kh 4M | Vt 8M | Vsc 12M | Wt 16M | Oh 17M..25M
    char* ws = (char*)d_ws;
    _Float16* Qh  = (_Float16*)(ws);
    _Float16* Kh  = (_Float16*)(ws + (4u << 20));
    _Float16* Vt  = (_Float16*)(ws + (8u << 20));
    _Float16* Vsc = (_Float16*)(ws + (12u << 20));
    _Float16* Wt  = (_Float16*)(ws + (16u << 20));
    _Float16* Oh  = (_Float16*)(ws + (17u << 20));

    proj_kernel<<<dim3(512, 4), 256, 0, stream>>>(
        query, Wq, bq, key, Wk, bk, value, Wv, bv, Wfc, Qh, Kh, Vt, Wt);
    stats_kernel<<<dim3(NH_, 8), 256, 0, stream>>>(Qh, Kh, Vt, Vsc);
    attn_kernel<<<dim3(NH_, 8), 256, 0, stream>>>(Qh, Kh, Vsc, Oh);
    fc_kernel<<<512, 256, 0, stream>>>(Oh, Wt, bfc, out);
}

// Round 8
// 178.141 us; speedup vs baseline: 4.0335x; 1.1321x over previous
//
#include <hip/hip_runtime.h>

// Problem constants: B=1, N=16, T=2048, E=64, H=4, D=16
#define N_ 16
#define T_ 2048
#define E_ 64
#define H_ 4
#define D_ 16
#define NH_ 64            // N_*H_
#define SEXP_ 0.18033688f // 0.125 * log2(e):  exp(s/8) == exp2(s*SEXP_)

typedef __attribute__((ext_vector_type(4))) _Float16 h4;
typedef __attribute__((ext_vector_type(8))) _Float16 h8;
typedef __attribute__((ext_vector_type(2))) __fp16 g2;
typedef __attribute__((ext_vector_type(4))) float f4;

#if __has_builtin(__builtin_amdgcn_exp2f)
__device__ inline float fast_exp2(float x) { return __builtin_amdgcn_exp2f(x); }
#else
__device__ inline float fast_exp2(float x) {
    float r; asm("v_exp_f32 %0, %1" : "=v"(r) : "v"(x)); return r;
}
#endif

// pack 4 floats -> h4 via two v_cvt_pkrtz_f16_f32
__device__ inline h4 pack4_f16(float a, float b, float c, float d) {
    union { g2 g[2]; h4 h; } u;
    u.g[0] = __builtin_amdgcn_cvt_pkrtz(a, b);
    u.g[1] = __builtin_amdgcn_cvt_pkrtz(c, d);
    return u.h;
}

// ---------------------------------------------------------------------------
// K1: fused projections (y=0 Q pre-scaled, y=1 K, y=2 V-transposed, y=3 Wfc^T)
// ---------------------------------------------------------------------------
__global__ __launch_bounds__(256) void proj_kernel(
    const float* __restrict__ xq, const float* __restrict__ Wq, const float* __restrict__ bq,
    const float* __restrict__ xk, const float* __restrict__ Wk, const float* __restrict__ bk,
    const float* __restrict__ xv, const float* __restrict__ Wv, const float* __restrict__ bv,
    const float* __restrict__ Wfc,
    _Float16* __restrict__ Qh, _Float16* __restrict__ Kh, _Float16* __restrict__ Vt,
    _Float16* __restrict__ Wt)
{
    int tid = threadIdx.x;
    int y = blockIdx.y;
    if (y == 3) {
        if (blockIdx.x < 16) {
            int k = blockIdx.x * 4 + (tid >> 6);
            int e = tid & 63;
            Wt[e * 64 + k] = (_Float16)Wfc[k * 64 + e];
        }
        return;
    }
    const float* x = (y == 0) ? xq : (y == 1) ? xk : xv;
    const float* W = (y == 0) ? Wq : (y == 1) ? Wk : Wv;
    const float* b = (y == 0) ? bq : (y == 1) ? bk : bv;
    const float sc = (y == 0) ? SEXP_ : 1.0f;

    __shared__ float Wl[D_ * D_];
    __shared__ float bl[D_];
    Wl[tid] = W[tid];
    if (tid < D_) bl[tid] = b[tid];
    __syncthreads();

    int r = blockIdx.x * 256 + tid;
    int h, t, n;
    if (y == 2) {          // t fastest: coalesced transposed stores
        t = r & (T_ - 1);
        h = (r >> 11) & (H_ - 1);
        n = r >> 13;
    } else {               // h fastest: coalesced reads
        h = r & (H_ - 1);
        t = (r >> 2) & (T_ - 1);
        n = r >> 13;
    }

    const float4* xp4 = reinterpret_cast<const float4*>(
        x + ((size_t)(n * T_ + t) * E_ + h * D_));
    float xv_[D_];
#pragma unroll
    for (int i = 0; i < 4; i++) {
        float4 v = xp4[i];
        xv_[4*i] = v.x; xv_[4*i+1] = v.y; xv_[4*i+2] = v.z; xv_[4*i+3] = v.w;
    }
    float acc[D_];
#pragma unroll
    for (int i = 0; i < D_; i++) acc[i] = bl[i];
#pragma unroll
    for (int j = 0; j < D_; j++) {
        float xj = xv_[j];
#pragma unroll
        for (int i = 0; i < D_; i++) acc[i] = fmaf(xj, Wl[j * D_ + i], acc[i]);
    }
    if (y == 2) {
        _Float16* vb = Vt + (size_t)(n * H_ + h) * D_ * T_ + t;
#pragma unroll
        for (int d = 0; d < D_; d++) vb[(size_t)d * T_] = (_Float16)acc[d];
    } else {
        _Float16 ob[16];
#pragma unroll
        for (int i = 0; i < D_; i++) ob[i] = (_Float16)(acc[i] * sc);
        _Float16* out = (y == 0) ? Qh : Kh;
        uint4* dst = reinterpret_cast<uint4*>(out + (size_t)((n * H_ + h) * T_ + t) * D_);
        dst[0] = reinterpret_cast<uint4*>(ob)[0];
        dst[1] = reinterpret_cast<uint4*>(ob)[1];
    }
}

// ---------------------------------------------------------------------------
// K2: stats — partial column sums Lp[z][nh][k] = sum_{q in z-chunk} exp2(S')
//     Wave holds 4 k-tiles, q-loop split x4 over blockIdx.z.
//     grid (NH, 8, 4) x 256 -> 8192 waves.
// ---------------------------------------------------------------------------
__global__ __launch_bounds__(256) void stats_kernel(
    const _Float16* __restrict__ Qh, const _Float16* __restrict__ Kh,
    float* __restrict__ Lp)
{
    int tid = threadIdx.x;
    int lane = tid & 63, wave = tid >> 6;
    int row = lane & 15, quad = lane >> 4;
    int nh = blockIdx.x;
    int kt0 = (blockIdx.y * 4 + wave) * 4;    // first of 4 k-tiles
    int z = blockIdx.z;
    const _Float16* Kb = Kh + (size_t)nh * T_ * D_;
    const _Float16* Qb = Qh + (size_t)nh * T_ * D_;

    h4 a[4];
#pragma unroll
    for (int j = 0; j < 4; j++)
        a[j] = *reinterpret_cast<const h4*>(Kb + ((kt0 + j) * 16 + row) * D_ + quad * 4);

    f4 l[4];
#pragma unroll
    for (int j = 0; j < 4; j++) l[j] = (f4){0.f, 0.f, 0.f, 0.f};
    f4 z4 = {0.f, 0.f, 0.f, 0.f};

    int q_lo = z * (T_ / 4), q_hi = q_lo + T_ / 4;
#pragma unroll 4
    for (int q0 = q_lo; q0 < q_hi; q0 += 16) {
        h4 b = *reinterpret_cast<const h4*>(Qb + (q0 + row) * D_ + quad * 4);
#pragma unroll
        for (int j = 0; j < 4; j++) {
            f4 s = __builtin_amdgcn_mfma_f32_16x16x16f16(a[j], b, z4, 0, 0, 0);
#pragma unroll
            for (int i = 0; i < 4; i++) l[j][i] += fast_exp2(s[i]);
        }
    }
    // butterfly sum over the 16 "q-row" lanes of each quad group
#pragma unroll
    for (int off = 1; off < 16; off <<= 1)
#pragma unroll
        for (int j = 0; j < 4; j++)
#pragma unroll
            for (int i = 0; i < 4; i++)
                l[j][i] += __shfl_xor(l[j][i], off, 64);

    if (row == 0) {
        float* lp = Lp + ((size_t)z * NH_ + nh) * T_;
#pragma unroll
        for (int j = 0; j < 4; j++)
            *reinterpret_cast<f4*>(lp + (kt0 + j) * 16 + quad * 4) = l[j];
    }
}

// ---------------------------------------------------------------------------
// K3: combine — l[k] = sum_z Lp[z][nh][k]; scale Vt in place by 1/l[k].
//     grid 128 x 256: block b -> nh=b>>1, k-half=(b&1); thread owns 4 k's.
// ---------------------------------------------------------------------------
__global__ __launch_bounds__(256) void combine_kernel(
    const float* __restrict__ Lp, _Float16* __restrict__ Vt)
{
    int nh = blockIdx.x >> 1;
    int k0 = (blockIdx.x & 1) * 1024 + threadIdx.x * 4;

    f4 s = {0.f, 0.f, 0.f, 0.f};
#pragma unroll
    for (int zz = 0; zz < 4; zz++) {
        f4 lv = *reinterpret_cast<const f4*>(Lp + ((size_t)zz * NH_ + nh) * T_ + k0);
        s[0] += lv[0]; s[1] += lv[1]; s[2] += lv[2]; s[3] += lv[3];
    }
    f4 r;
#pragma unroll
    for (int i = 0; i < 4; i++) r[i] = 1.0f / s[i];

    _Float16* vb = Vt + (size_t)nh * D_ * T_ + k0;
#pragma unroll
    for (int d = 0; d < D_; d++) {
        union { uint2 u; _Float16 hh[4]; } v;
        v.u = *reinterpret_cast<const uint2*>(vb + (size_t)d * T_);
        h4 sv = pack4_f16((float)v.hh[0] * r[0], (float)v.hh[1] * r[1],
                          (float)v.hh[2] * r[2], (float)v.hh[3] * r[3]);
        union { h4 h; uint2 u; } o; o.h = sv;
        *reinterpret_cast<uint2*>(vb + (size_t)d * T_) = o.u;
    }
}

// ---------------------------------------------------------------------------
// K4: attn — partial O over k-range; k-loop split x2 over blockIdx.z.
//     Wave holds 4 q-tiles.  Per 32-k: two k16 S-MFMAs with PERMUTED K rows
//     so stacked C-outputs form the A-fragment of one 16x16x32 PV MFMA.
//     grid (NH, 8, 2) x 256 -> 4096 waves.  PO fp32 [z][N][T][E].
// ---------------------------------------------------------------------------
__global__ __launch_bounds__(256) void attn_kernel(
    const _Float16* __restrict__ Qh, const _Float16* __restrict__ Kh,
    const _Float16* __restrict__ Vsc, float* __restrict__ PO)
{
    int tid = threadIdx.x;
    int lane = tid & 63, wave = tid >> 6;
    int row = lane & 15, quad = lane >> 4;
    int nh = blockIdx.x;
    int qt0 = (blockIdx.y * 4 + wave) * 4;    // first of 4 q-tiles
    int z = blockIdx.z;
    const _Float16* Kb = Kh + (size_t)nh * T_ * D_;
    const _Float16* Qb = Qh + (size_t)nh * T_ * D_;
    const _Float16* Vb = Vsc + (size_t)nh * D_ * T_ + (size_t)row * T_;

    h4 b[4];
#pragma unroll
    for (int j = 0; j < 4; j++)
        b[j] = *reinterpret_cast<const h4*>(Qb + ((qt0 + j) * 16 + row) * D_ + quad * 4);

    f4 o[4];
#pragma unroll
    for (int j = 0; j < 4; j++) o[j] = (f4){0.f, 0.f, 0.f, 0.f};
    f4 z4 = {0.f, 0.f, 0.f, 0.f};

    int pr = ((row & 12) << 1) | (row & 3);   // permuted K-row offset

    int k_lo = z * (T_ / 2), k_hi = k_lo + T_ / 2;
#pragma unroll 2
    for (int k0 = k_lo; k0 < k_hi; k0 += 32) {
        h4 a0 = *reinterpret_cast<const h4*>(Kb + (k0 + pr) * D_ + quad * 4);
        h4 a1 = *reinterpret_cast<const h4*>(Kb + (k0 + pr + 4) * D_ + quad * 4);
        h8 v = *reinterpret_cast<const h8*>(Vb + k0 + quad * 8);
#pragma unroll
        for (int j = 0; j < 4; j++) {
            f4 s0 = __builtin_amdgcn_mfma_f32_16x16x16f16(a0, b[j], z4, 0, 0, 0);
            f4 s1 = __builtin_amdgcn_mfma_f32_16x16x16f16(a1, b[j], z4, 0, 0, 0);
            union { h4 h[2]; h8 h8v; } p;
            p.h[0] = pack4_f16(fast_exp2(s0[0]), fast_exp2(s0[1]),
                               fast_exp2(s0[2]), fast_exp2(s0[3]));
            p.h[1] = pack4_f16(fast_exp2(s1[0]), fast_exp2(s1[1]),
                               fast_exp2(s1[2]), fast_exp2(s1[3]));
            o[j] = __builtin_amdgcn_mfma_f32_16x16x32_f16(p.h8v, v, o[j], 0, 0, 0);
        }
    }
    int n = nh >> 2, h = nh & 3;
    float* po = PO + (size_t)z * N_ * T_ * E_ + (size_t)n * T_ * E_ + h * D_ + row;
#pragma unroll
    for (int j = 0; j < 4; j++)
#pragma unroll
        for (int i = 0; i < 4; i++) {
            int q0 = (qt0 + j) * 16 + quad * 4 + i;
            po[(size_t)q0 * E_] = o[j][i];
        }
}

// ---------------------------------------------------------------------------
// K5: fc — out = (PO0+PO1) @ Wfc + bfc via 16x16x32 MFMA on Wt.
//     wave: one 16-row M-tile; 2048 tiles -> 512 blocks.
// ---------------------------------------------------------------------------
__global__ __launch_bounds__(256) void fc_kernel(
    const float* __restrict__ PO0, const float* __restrict__ PO1,
    const _Float16* __restrict__ Wt,
    const float* __restrict__ bfc, float* __restrict__ out)
{
    int tid = threadIdx.x;
    int lane = tid & 63, wave = tid >> 6;
    int row = lane & 15, quad = lane >> 4;
    int g = blockIdx.x * 4 + wave;             // M-tile id, 2048 total
    int r0 = g * 16;

    size_t base = (size_t)(r0 + row) * E_;
    const f4* p0 = reinterpret_cast<const f4*>(PO0 + base);
    const f4* p1 = reinterpret_cast<const f4*>(PO1 + base);

    h8 a[2];
#pragma unroll
    for (int half = 0; half < 2; half++) {
        f4 u = p0[half * 8 + quad * 2],     w = p1[half * 8 + quad * 2];
        f4 u2 = p0[half * 8 + quad * 2 + 1], w2 = p1[half * 8 + quad * 2 + 1];
        union { h4 h[2]; h8 v; } pk;
        pk.h[0] = pack4_f16(u[0] + w[0], u[1] + w[1], u[2] + w[2], u[3] + w[3]);
        pk.h[1] = pack4_f16(u2[0] + w2[0], u2[1] + w2[1], u2[2] + w2[2], u2[3] + w2[3]);
        a[half] = pk.v;
    }

    f4 acc[4];
#pragma unroll
    for (int ne = 0; ne < 4; ne++) {
        const _Float16* wtb = Wt + (size_t)(ne * 16 + row) * 64;
        h8 b0 = *reinterpret_cast<const h8*>(wtb + quad * 8);
        h8 b1 = *reinterpret_cast<const h8*>(wtb + 32 + quad * 8);
        acc[ne] = __builtin_amdgcn_mfma_f32_16x16x32_f16(a[0], b0, (f4){0.f,0.f,0.f,0.f}, 0, 0, 0);
        acc[ne] = __builtin_amdgcn_mfma_f32_16x16x32_f16(a[1], b1, acc[ne], 0, 0, 0);
    }
#pragma unroll
    for (int ne = 0; ne < 4; ne++) {
        float bias = bfc[ne * 16 + row];
#pragma unroll
        for (int i = 0; i < 4; i++)
            out[(size_t)(r0 + quad * 4 + i) * E_ + ne * 16 + row] = acc[ne][i] + bias;
    }
}

extern "C" void kernel_launch(void* const* d_in, const int* in_sizes, int n_in,
                              void* d_out, int out_size, void* d_ws, size_t ws_size,
                              hipStream_t stream) {
    (void)in_sizes; (void)n_in; (void)out_size; (void)ws_size;
    const float* value = (const float*)d_in[0];
    const float* key   = (const float*)d_in[1];
    const float* query = (const float*)d_in[2];
    const float* Wq    = (const float*)d_in[3];
    const float* bq    = (const float*)d_in[4];
    const float* Wk    = (const float*)d_in[5];
    const float* bk    = (const float*)d_in[6];
    const float* Wv    = (const float*)d_in[7];
    const float* bv    = (const float*)d_in[8];
    const float* Wfc   = (const float*)d_in[9];
    const float* bfc   = (const float*)d_in[10];
    float* out = (float*)d_out;

    // ws bytes: Qh 0-4M | Kh 4-8M | Vt 8-12M (scaled in place) | Wt 12M |
    //           Lp 13-15M | PO 15-31M (2 x 8M fp32)
    char* ws = (char*)d_ws;
    _Float16* Qh  = (_Float16*)(ws);
    _Float16* Kh  = (_Float16*)(ws + (4u << 20));
    _Float16* Vt  = (_Float16*)(ws + (8u << 20));
    _Float16* Wt  = (_Float16*)(ws + (12u << 20));
    float*    Lp  = (float*)   (ws + (13u << 20));
    float*    PO  = (float*)   (ws + (15u << 20));
    float*    PO0 = PO;
    float*    PO1 = PO + (size_t)N_ * T_ * E_;

    proj_kernel<<<dim3(512, 4), 256, 0, stream>>>(
        query, Wq, bq, key, Wk, bk, value, Wv, bv, Wfc, Qh, Kh, Vt, Wt);
    stats_kernel<<<dim3(NH_, 8, 4), 256, 0, stream>>>(Qh, Kh, Lp);
    combine_kernel<<<128, 256, 0, stream>>>(Lp, Vt);
    attn_kernel<<<dim3(NH_, 8, 2), 256, 0, stream>>>(Qh, Kh, Vt, PO);
    fc_kernel<<<512, 256, 0, stream>>>(PO0, PO1, Wt, bfc, out);
}

// Round 9
// 176.445 us; speedup vs baseline: 4.0722x; 1.0096x over previous
//
#include <hip/hip_runtime.h>

// Problem constants: B=1, N=16, T=2048, E=64, H=4, D=16
#define N_ 16
#define T_ 2048
#define E_ 64
#define H_ 4
#define D_ 16
#define NH_ 64            // N_*H_
#define SEXP_ 0.18033688f // 0.125 * log2(e):  exp(s/8) == exp2(s*SEXP_)

typedef __attribute__((ext_vector_type(4))) _Float16 h4;
typedef __attribute__((ext_vector_type(8))) _Float16 h8;
typedef __attribute__((ext_vector_type(2))) __fp16 g2;
typedef __attribute__((ext_vector_type(4))) float f4;

#if __has_builtin(__builtin_amdgcn_exp2f)
__device__ inline float fast_exp2(float x) { return __builtin_amdgcn_exp2f(x); }
#else
__device__ inline float fast_exp2(float x) {
    float r; asm("v_exp_f32 %0, %1" : "=v"(r) : "v"(x)); return r;
}
#endif

// pack 4 floats -> h4 via two v_cvt_pkrtz_f16_f32
__device__ inline h4 pack4_f16(float a, float b, float c, float d) {
    union { g2 g[2]; h4 h; } u;
    u.g[0] = __builtin_amdgcn_cvt_pkrtz(a, b);
    u.g[1] = __builtin_amdgcn_cvt_pkrtz(c, d);
    return u.h;
}

// ---------------------------------------------------------------------------
// K1: fused projections (y=0 Q pre-scaled, y=1 K, y=2 V-transposed, y=3 Wfc^T)
// ---------------------------------------------------------------------------
__global__ __launch_bounds__(256) void proj_kernel(
    const float* __restrict__ xq, const float* __restrict__ Wq, const float* __restrict__ bq,
    const float* __restrict__ xk, const float* __restrict__ Wk, const float* __restrict__ bk,
    const float* __restrict__ xv, const float* __restrict__ Wv, const float* __restrict__ bv,
    const float* __restrict__ Wfc,
    _Float16* __restrict__ Qh, _Float16* __restrict__ Kh, _Float16* __restrict__ Vt,
    _Float16* __restrict__ Wt)
{
    int tid = threadIdx.x;
    int y = blockIdx.y;
    if (y == 3) {
        if (blockIdx.x < 16) {
            int k = blockIdx.x * 4 + (tid >> 6);
            int e = tid & 63;
            Wt[e * 64 + k] = (_Float16)Wfc[k * 64 + e];
        }
        return;
    }
    const float* x = (y == 0) ? xq : (y == 1) ? xk : xv;
    const float* W = (y == 0) ? Wq : (y == 1) ? Wk : Wv;
    const float* b = (y == 0) ? bq : (y == 1) ? bk : bv;
    const float sc = (y == 0) ? SEXP_ : 1.0f;

    __shared__ float Wl[D_ * D_];
    __shared__ float bl[D_];
    Wl[tid] = W[tid];
    if (tid < D_) bl[tid] = b[tid];
    __syncthreads();

    int r = blockIdx.x * 256 + tid;
    int h, t, n;
    if (y == 2) {          // t fastest: coalesced transposed stores
        t = r & (T_ - 1);
        h = (r >> 11) & (H_ - 1);
        n = r >> 13;
    } else {               // h fastest: coalesced reads
        h = r & (H_ - 1);
        t = (r >> 2) & (T_ - 1);
        n = r >> 13;
    }

    const float4* xp4 = reinterpret_cast<const float4*>(
        x + ((size_t)(n * T_ + t) * E_ + h * D_));
    float xv_[D_];
#pragma unroll
    for (int i = 0; i < 4; i++) {
        float4 v = xp4[i];
        xv_[4*i] = v.x; xv_[4*i+1] = v.y; xv_[4*i+2] = v.z; xv_[4*i+3] = v.w;
    }
    float acc[D_];
#pragma unroll
    for (int i = 0; i < D_; i++) acc[i] = bl[i];
#pragma unroll
    for (int j = 0; j < D_; j++) {
        float xj = xv_[j];
#pragma unroll
        for (int i = 0; i < D_; i++) acc[i] = fmaf(xj, Wl[j * D_ + i], acc[i]);
    }
    if (y == 2) {
        _Float16* vb = Vt + (size_t)(n * H_ + h) * D_ * T_ + t;
#pragma unroll
        for (int d = 0; d < D_; d++) vb[(size_t)d * T_] = (_Float16)acc[d];
    } else {
        _Float16 ob[16];
#pragma unroll
        for (int i = 0; i < D_; i++) ob[i] = (_Float16)(acc[i] * sc);
        _Float16* out = (y == 0) ? Qh : Kh;
        uint4* dst = reinterpret_cast<uint4*>(out + (size_t)((n * H_ + h) * T_ + t) * D_);
        dst[0] = reinterpret_cast<uint4*>(ob)[0];
        dst[1] = reinterpret_cast<uint4*>(ob)[1];
    }
}

// ---------------------------------------------------------------------------
// K2: stats — partial column sums Lp[z][nh][k] = sum_{q in z-chunk} exp2(S')
//     Wave holds 4 k-tiles, q-loop split x4 over blockIdx.z.
//     grid (NH, 8, 4) x 256 -> 8192 waves.
// ---------------------------------------------------------------------------
__global__ __launch_bounds__(256) void stats_kernel(
    const _Float16* __restrict__ Qh, const _Float16* __restrict__ Kh,
    float* __restrict__ Lp)
{
    int tid = threadIdx.x;
    int lane = tid & 63, wave = tid >> 6;
    int row = lane & 15, quad = lane >> 4;
    int nh = blockIdx.x;
    int kt0 = (blockIdx.y * 4 + wave) * 4;    // first of 4 k-tiles
    int z = blockIdx.z;
    const _Float16* Kb = Kh + (size_t)nh * T_ * D_;
    const _Float16* Qb = Qh + (size_t)nh * T_ * D_;

    h4 a[4];
#pragma unroll
    for (int j = 0; j < 4; j++)
        a[j] = *reinterpret_cast<const h4*>(Kb + ((kt0 + j) * 16 + row) * D_ + quad * 4);

    f4 l[4];
#pragma unroll
    for (int j = 0; j < 4; j++) l[j] = (f4){0.f, 0.f, 0.f, 0.f};
    f4 z4 = {0.f, 0.f, 0.f, 0.f};

    int q_lo = z * (T_ / 4), q_hi = q_lo + T_ / 4;
#pragma unroll 4
    for (int q0 = q_lo; q0 < q_hi; q0 += 16) {
        h4 b = *reinterpret_cast<const h4*>(Qb + (q0 + row) * D_ + quad * 4);
#pragma unroll
        for (int j = 0; j < 4; j++) {
            f4 s = __builtin_amdgcn_mfma_f32_16x16x16f16(a[j], b, z4, 0, 0, 0);
#pragma unroll
            for (int i = 0; i < 4; i++) l[j][i] += fast_exp2(s[i]);
        }
    }
    // butterfly sum over the 16 "q-row" lanes of each quad group
#pragma unroll
    for (int off = 1; off < 16; off <<= 1)
#pragma unroll
        for (int j = 0; j < 4; j++)
#pragma unroll
            for (int i = 0; i < 4; i++)
                l[j][i] += __shfl_xor(l[j][i], off, 64);

    if (row == 0) {
        float* lp = Lp + ((size_t)z * NH_ + nh) * T_;
#pragma unroll
        for (int j = 0; j < 4; j++)
            *reinterpret_cast<f4*>(lp + (kt0 + j) * 16 + quad * 4) = l[j];
    }
}

// ---------------------------------------------------------------------------
// K3: combine — l[k] = sum_z Lp[z][nh][k]; scale Vt in place by 1/l[k].
//     grid 128 x 256: block b -> nh=b>>1, k-half=(b&1); thread owns 4 k's.
// ---------------------------------------------------------------------------
__global__ __launch_bounds__(256) void combine_kernel(
    const float* __restrict__ Lp, _Float16* __restrict__ Vt)
{
    int nh = blockIdx.x >> 1;
    int k0 = (blockIdx.x & 1) * 1024 + threadIdx.x * 4;

    f4 s = {0.f, 0.f, 0.f, 0.f};
#pragma unroll
    for (int zz = 0; zz < 4; zz++) {
        f4 lv = *reinterpret_cast<const f4*>(Lp + ((size_t)zz * NH_ + nh) * T_ + k0);
        s[0] += lv[0]; s[1] += lv[1]; s[2] += lv[2]; s[3] += lv[3];
    }
    f4 r;
#pragma unroll
    for (int i = 0; i < 4; i++) r[i] = 1.0f / s[i];

    _Float16* vb = Vt + (size_t)nh * D_ * T_ + k0;
#pragma unroll
    for (int d = 0; d < D_; d++) {
        union { uint2 u; _Float16 hh[4]; } v;
        v.u = *reinterpret_cast<const uint2*>(vb + (size_t)d * T_);
        h4 sv = pack4_f16((float)v.hh[0] * r[0], (float)v.hh[1] * r[1],
                          (float)v.hh[2] * r[2], (float)v.hh[3] * r[3]);
        union { h4 h; uint2 u; } o; o.h = sv;
        *reinterpret_cast<uint2*>(vb + (size_t)d * T_) = o.u;
    }
}

// ---------------------------------------------------------------------------
// K4: attn — partial O over k-range; k-loop split x4 over blockIdx.z.
//     Wave holds 4 q-tiles.  Per 32-k: two k16 S-MFMAs with PERMUTED K rows
//     so stacked C-outputs form the A-fragment of one 16x16x32 PV MFMA.
//     grid (NH, 8, 4) x 256 -> 8192 waves (8 blk/CU).  PO fp32 [z][N][T][E].
// ---------------------------------------------------------------------------
__global__ __launch_bounds__(256) void attn_kernel(
    const _Float16* __restrict__ Qh, const _Float16* __restrict__ Kh,
    const _Float16* __restrict__ Vsc, float* __restrict__ PO)
{
    int tid = threadIdx.x;
    int lane = tid & 63, wave = tid >> 6;
    int row = lane & 15, quad = lane >> 4;
    int nh = blockIdx.x;
    int qt0 = (blockIdx.y * 4 + wave) * 4;    // first of 4 q-tiles
    int z = blockIdx.z;
    const _Float16* Kb = Kh + (size_t)nh * T_ * D_;
    const _Float16* Qb = Qh + (size_t)nh * T_ * D_;
    const _Float16* Vb = Vsc + (size_t)nh * D_ * T_ + (size_t)row * T_;

    h4 b[4];
#pragma unroll
    for (int j = 0; j < 4; j++)
        b[j] = *reinterpret_cast<const h4*>(Qb + ((qt0 + j) * 16 + row) * D_ + quad * 4);

    f4 o[4];
#pragma unroll
    for (int j = 0; j < 4; j++) o[j] = (f4){0.f, 0.f, 0.f, 0.f};
    f4 z4 = {0.f, 0.f, 0.f, 0.f};

    int pr = ((row & 12) << 1) | (row & 3);   // permuted K-row offset

    int k_lo = z * (T_ / 4), k_hi = k_lo + T_ / 4;
#pragma unroll 2
    for (int k0 = k_lo; k0 < k_hi; k0 += 32) {
        h4 a0 = *reinterpret_cast<const h4*>(Kb + (k0 + pr) * D_ + quad * 4);
        h4 a1 = *reinterpret_cast<const h4*>(Kb + (k0 + pr + 4) * D_ + quad * 4);
        h8 v = *reinterpret_cast<const h8*>(Vb + k0 + quad * 8);
#pragma unroll
        for (int j = 0; j < 4; j++) {
            f4 s0 = __builtin_amdgcn_mfma_f32_16x16x16f16(a0, b[j], z4, 0, 0, 0);
            f4 s1 = __builtin_amdgcn_mfma_f32_16x16x16f16(a1, b[j], z4, 0, 0, 0);
            union { h4 h[2]; h8 h8v; } p;
            p.h[0] = pack4_f16(fast_exp2(s0[0]), fast_exp2(s0[1]),
                               fast_exp2(s0[2]), fast_exp2(s0[3]));
            p.h[1] = pack4_f16(fast_exp2(s1[0]), fast_exp2(s1[1]),
                               fast_exp2(s1[2]), fast_exp2(s1[3]));
            o[j] = __builtin_amdgcn_mfma_f32_16x16x32_f16(p.h8v, v, o[j], 0, 0, 0);
        }
    }
    int n = nh >> 2, h = nh & 3;
    float* po = PO + (size_t)z * N_ * T_ * E_ + (size_t)n * T_ * E_ + h * D_ + row;
#pragma unroll
    for (int j = 0; j < 4; j++)
#pragma unroll
        for (int i = 0; i < 4; i++) {
            int q0 = (qt0 + j) * 16 + quad * 4 + i;
            po[(size_t)q0 * E_] = o[j][i];
        }
}

// ---------------------------------------------------------------------------
// K5: fc — out = (sum_z PO[z]) @ Wfc + bfc via 16x16x32 MFMA on Wt.
//     wave: one 16-row M-tile; 2048 tiles -> 512 blocks.
// ---------------------------------------------------------------------------
__global__ __launch_bounds__(256) void fc_kernel(
    const float* __restrict__ PO, const _Float16* __restrict__ Wt,
    const float* __restrict__ bfc, float* __restrict__ out)
{
    int tid = threadIdx.x;
    int lane = tid & 63, wave = tid >> 6;
    int row = lane & 15, quad = lane >> 4;
    int g = blockIdx.x * 4 + wave;             // M-tile id, 2048 total
    int r0 = g * 16;

    size_t base = (size_t)(r0 + row) * E_;
    const size_t zstride = (size_t)N_ * T_ * E_ / 4;   // in f4 units

    h8 a[2];
#pragma unroll
    for (int half = 0; half < 2; half++) {
        f4 u0 = {0.f,0.f,0.f,0.f}, u1 = {0.f,0.f,0.f,0.f};
#pragma unroll
        for (int zz = 0; zz < 4; zz++) {
            const f4* p = reinterpret_cast<const f4*>(PO) + zz * zstride + base / 4;
            f4 w0 = p[half * 8 + quad * 2];
            f4 w1 = p[half * 8 + quad * 2 + 1];
#pragma unroll
            for (int i = 0; i < 4; i++) { u0[i] += w0[i]; u1[i] += w1[i]; }
        }
        union { h4 h[2]; h8 v; } pk;
        pk.h[0] = pack4_f16(u0[0], u0[1], u0[2], u0[3]);
        pk.h[1] = pack4_f16(u1[0], u1[1], u1[2], u1[3]);
        a[half] = pk.v;
    }

    f4 acc[4];
#pragma unroll
    for (int ne = 0; ne < 4; ne++) {
        const _Float16* wtb = Wt + (size_t)(ne * 16 + row) * 64;
        h8 b0 = *reinterpret_cast<const h8*>(wtb + quad * 8);
        h8 b1 = *reinterpret_cast<const h8*>(wtb + 32 + quad * 8);
        acc[ne] = __builtin_amdgcn_mfma_f32_16x16x32_f16(a[0], b0, (f4){0.f,0.f,0.f,0.f}, 0, 0, 0);
        acc[ne] = __builtin_amdgcn_mfma_f32_16x16x32_f16(a[1], b1, acc[ne], 0, 0, 0);
    }
#pragma unroll
    for (int ne = 0; ne < 4; ne++) {
        float bias = bfc[ne * 16 + row];
#pragma unroll
        for (int i = 0; i < 4; i++)
            out[(size_t)(r0 + quad * 4 + i) * E_ + ne * 16 + row] = acc[ne][i] + bias;
    }
}

extern "C" void kernel_launch(void* const* d_in, const int* in_sizes, int n_in,
                              void* d_out, int out_size, void* d_ws, size_t ws_size,
                              hipStream_t stream) {
    (void)in_sizes; (void)n_in; (void)out_size; (void)ws_size;
    const float* value = (const float*)d_in[0];
    const float* key   = (const float*)d_in[1];
    const float* query = (const float*)d_in[2];
    const float* Wq    = (const float*)d_in[3];
    const float* bq    = (const float*)d_in[4];
    const float* Wk    = (const float*)d_in[5];
    const float* bk    = (const float*)d_in[6];
    const float* Wv    = (const float*)d_in[7];
    const float* bv    = (const float*)d_in[8];
    const float* Wfc   = (const float*)d_in[9];
    const float* bfc   = (const float*)d_in[10];
    float* out = (float*)d_out;

    // ws bytes: Qh 0-4M | Kh 4-8M | Vt 8-12M (scaled in place) | Wt 12M |
    //           Lp 13-15M | PO 15-47M (4 x 8M fp32)
    char* ws = (char*)d_ws;
    _Float16* Qh  = (_Float16*)(ws);
    _Float16* Kh  = (_Float16*)(ws + (4u << 20));
    _Float16* Vt  = (_Float16*)(ws + (8u << 20));
    _Float16* Wt  = (_Float16*)(ws + (12u << 20));
    float*    Lp  = (float*)   (ws + (13u << 20));
    float*    PO  = (float*)   (ws + (15u << 20));

    proj_kernel<<<dim3(512, 4), 256, 0, stream>>>(
        query, Wq, bq, key, Wk, bk, value, Wv, bv, Wfc, Qh, Kh, Vt, Wt);
    stats_kernel<<<dim3(NH_, 8, 4), 256, 0, stream>>>(Qh, Kh, Lp);
    combine_kernel<<<128, 256, 0, stream>>>(Lp, Vt);
    attn_kernel<<<dim3(NH_, 8, 4), 256, 0, stream>>>(Qh, Kh, Vt, PO);
    fc_kernel<<<512, 256, 0, stream>>>(PO, Wt, bfc, out);
}